// Round 1
// baseline (155.016 us; speedup 1.0000x reference)
//
#include <hip/hip_runtime.h>
#include <stdint.h>

#define S_TOT 4096
#define CH 128
#define NH 4
#define DH 32

typedef __attribute__((ext_vector_type(4))) float f32x4;
typedef __attribute__((ext_vector_type(8))) short s16x8;
typedef __attribute__((ext_vector_type(4))) short s16x4;

__device__ __forceinline__ unsigned short f2bf(float f){
  union { float f; unsigned u; } v; v.f = f;
  unsigned r = v.u + 0x7fffu + ((v.u >> 16) & 1u);
  return (unsigned short)(r >> 16);
}
__device__ __forceinline__ unsigned pk2(float a, float b){
  return (unsigned)f2bf(a) | ((unsigned)f2bf(b) << 16);
}

// ---------------- kernel 1: fp32 -> bf16 weight conversion ----------------
__global__ void k_prep(const float* __restrict__ qkvw, const float* __restrict__ projw,
                       unsigned short* __restrict__ wq, unsigned short* __restrict__ wp){
  int i = blockIdx.x * 256 + threadIdx.x;
  if (i < 384*128) wq[i] = f2bf(qkvw[i]);
  int j = i - 384*128;
  if (j >= 0 && j < 128*128) wp[j] = f2bf(projw[j]);
}

// ---------------- kernel 2: groupnorm stats (mean, rstd per (b,g)) ----------------
__global__ void k_gnstats(const float* __restrict__ x, float* __restrict__ stats){
  int bg = blockIdx.x; // b*32+g ; group = 4 contiguous channels * 4096 = 16384 floats
  const float4* p = (const float4*)(x + (size_t)bg * 16384);
  float s = 0.f, ss = 0.f;
  #pragma unroll
  for (int i = 0; i < 16; ++i){
    float4 v = p[threadIdx.x + i*256];
    s  += v.x + v.y + v.z + v.w;
    ss += v.x*v.x + v.y*v.y + v.z*v.z + v.w*v.w;
  }
  #pragma unroll
  for (int m = 1; m < 64; m <<= 1){ s += __shfl_xor(s, m); ss += __shfl_xor(ss, m); }
  __shared__ float red[8];
  int wid = threadIdx.x >> 6;
  if ((threadIdx.x & 63) == 0){ red[wid*2] = s; red[wid*2+1] = ss; }
  __syncthreads();
  if (threadIdx.x == 0){
    float S = red[0]+red[2]+red[4]+red[6], SS = red[1]+red[3]+red[5]+red[7];
    float mean = S * (1.f/16384.f);
    float var  = SS * (1.f/16384.f) - mean*mean;
    stats[bg*2]   = mean;
    stats[bg*2+1] = rsqrtf(var + 1e-5f);
  }
}

// ---------------- kernel 3: apply GN + transpose to hT [B][S][C] bf16 ----------------
__global__ void k_gnapply(const float* __restrict__ x, const float* __restrict__ stats,
                          const float* __restrict__ nw, const float* __restrict__ nb,
                          unsigned short* __restrict__ hT){
  __shared__ float lds[64*129];
  int b  = blockIdx.x >> 6;
  int s0 = (blockIdx.x & 63) * 64;
  int sid = threadIdx.x & 63, cg = threadIdx.x >> 6;
  #pragma unroll 4
  for (int c4 = 0; c4 < 32; ++c4){
    int c = c4*4 + cg;
    float mean = stats[(b*32 + c4)*2], rstd = stats[(b*32 + c4)*2 + 1];
    float v = x[((size_t)(b*CH + c))*S_TOT + s0 + sid];
    v = (v - mean) * rstd * nw[c] + nb[c];
    lds[sid*129 + c] = v;
  }
  __syncthreads();
  int row = threadIdx.x >> 2, q = threadIdx.x & 3, c0 = q*32;
  unsigned short* dst = hT + ((size_t)(b*S_TOT) + s0 + row) * CH + c0;
  const float* src = lds + row*129 + c0;
  #pragma unroll
  for (int cc = 0; cc < 4; ++cc){
    uint4 w;
    w.x = pk2(src[cc*8+0], src[cc*8+1]);
    w.y = pk2(src[cc*8+2], src[cc*8+3]);
    w.z = pk2(src[cc*8+4], src[cc*8+5]);
    w.w = pk2(src[cc*8+6], src[cc*8+7]);
    *(uint4*)(dst + cc*8) = w;
  }
}

// ---------------- kernel 4: QKV GEMM (bf16 MFMA) ----------------
// D[o][s] = sum_c Wq[o][c] * hT[s][c];  +bias; q scaled by scale*log2e; q/k stored [b][h][s][d], v stored [b][h][d][s]
__global__ void k_qkv(const unsigned short* __restrict__ hT, const unsigned short* __restrict__ wq,
                      const float* __restrict__ qkvb,
                      unsigned short* __restrict__ qT, unsigned short* __restrict__ kT,
                      unsigned short* __restrict__ vv){
  const float SC = 0.17677669529663687f * 1.4426950408889634f; // (1/sqrt(32)) * log2(e)
  int lane = threadIdx.x & 63, wid = threadIdx.x >> 6;
  int lo = lane & 15, hi = lane >> 4;
  int b  = blockIdx.z;
  int o0 = blockIdx.y * 64 + wid * 16;
  int sb = blockIdx.x * 64;
  s16x8 af[4];
  #pragma unroll
  for (int kk = 0; kk < 4; ++kk)
    af[kk] = *(const s16x8*)(wq + (size_t)(o0+lo)*CH + kk*32 + hi*8);
  #pragma unroll
  for (int st = 0; st < 4; ++st){
    int s0 = sb + st*16;
    const unsigned short* hrow = hT + ((size_t)(b*S_TOT) + s0 + lo) * CH + hi*8;
    f32x4 acc = {0.f,0.f,0.f,0.f};
    #pragma unroll
    for (int kk = 0; kk < 4; ++kk){
      s16x8 bfr = *(const s16x8*)(hrow + kk*32);
      acc = __builtin_amdgcn_mfma_f32_16x16x32_bf16(af[kk], bfr, acc, 0, 0, 0);
    }
    int s = s0 + lo;
    #pragma unroll
    for (int r = 0; r < 4; ++r){
      int o = o0 + hi*4 + r;
      float val = acc[r] + qkvb[o];
      if (o < 128){
        int h = o >> 5, d = o & 31;
        qT[(((size_t)(b*NH + h))*S_TOT + s)*DH + d] = f2bf(val * SC);
      } else if (o < 256){
        int o2 = o - 128, h = o2 >> 5, d = o2 & 31;
        kT[(((size_t)(b*NH + h))*S_TOT + s)*DH + d] = f2bf(val);
      } else {
        int o3 = o - 256, h = o3 >> 5, d = o3 & 31;
        vv[(((size_t)(b*NH + h))*DH + d)*S_TOT + s] = f2bf(val);
      }
    }
  }
}

// ---------------- kernel 5: flash attention ----------------
// per wave: 2 s-tiles (32 queries). Swapped QK^T: Pt[t][s] = K^T x Q. Online softmax in exp2 domain.
__global__ void __launch_bounds__(256) k_attn(const unsigned short* __restrict__ qT,
                                              const unsigned short* __restrict__ kT,
                                              const unsigned short* __restrict__ vv,
                                              unsigned short* __restrict__ aoT){
  int lane = threadIdx.x & 63, wid = threadIdx.x >> 6;
  int lo = lane & 15, hi = lane >> 4;
  int bh = blockIdx.x;           // wgid%8 == head -> one head per XCD
  int sw = blockIdx.y * 128 + wid * 32;
  const unsigned short* qh = qT + (size_t)bh * S_TOT * DH;
  const unsigned short* kh = kT + (size_t)bh * S_TOT * DH;
  const unsigned short* vh = vv + (size_t)bh * DH * S_TOT;
  unsigned short* aoh = aoT + (size_t)bh * S_TOT * DH;

  s16x8 qf0 = *(const s16x8*)(qh + (size_t)(sw + lo)*DH + hi*8);
  s16x8 qf1 = *(const s16x8*)(qh + (size_t)(sw + 16 + lo)*DH + hi*8);
  f32x4 acc00 = {0.f,0.f,0.f,0.f}, acc01 = {0.f,0.f,0.f,0.f};
  f32x4 acc10 = {0.f,0.f,0.f,0.f}, acc11 = {0.f,0.f,0.f,0.f};
  float m0 = -1e30f, m1 = -1e30f, l0 = 0.f, l1 = 0.f;

  for (int t0 = 0; t0 < S_TOT; t0 += 32){
    s16x8 kf0 = *(const s16x8*)(kh + (size_t)(t0 + lo)*DH + hi*8);
    s16x8 kf1 = *(const s16x8*)(kh + (size_t)(t0 + 16 + lo)*DH + hi*8);
    // V fragments: B-slot (hi,j): t = t0 + (j<4 ? 4*hi+j : 16+4*hi+(j-4)), col d = lo (+16)
    s16x4 va0 = *(const s16x4*)(vh + (size_t)lo*S_TOT + t0 + hi*4);
    s16x4 vb0 = *(const s16x4*)(vh + (size_t)lo*S_TOT + t0 + 16 + hi*4);
    s16x4 va1 = *(const s16x4*)(vh + (size_t)(lo+16)*S_TOT + t0 + hi*4);
    s16x4 vb1 = *(const s16x4*)(vh + (size_t)(lo+16)*S_TOT + t0 + 16 + hi*4);
    s16x8 vf0 = __builtin_shufflevector(va0, vb0, 0,1,2,3,4,5,6,7);
    s16x8 vf1 = __builtin_shufflevector(va1, vb1, 0,1,2,3,4,5,6,7);

    auto step = [&](const s16x8& qf, f32x4& a0, f32x4& a1, float& m, float& l){
      f32x4 z = {0.f,0.f,0.f,0.f};
      f32x4 p0 = __builtin_amdgcn_mfma_f32_16x16x32_bf16(kf0, qf, z, 0, 0, 0);
      f32x4 p1 = __builtin_amdgcn_mfma_f32_16x16x32_bf16(kf1, qf, z, 0, 0, 0);
      float cm = fmaxf(fmaxf(fmaxf(p0[0],p0[1]),fmaxf(p0[2],p0[3])),
                       fmaxf(fmaxf(p1[0],p1[1]),fmaxf(p1[2],p1[3])));
      cm = fmaxf(cm, __shfl_xor(cm, 16));
      cm = fmaxf(cm, __shfl_xor(cm, 32));
      float mn = fmaxf(m, cm);
      float al = exp2f(m - mn);
      m = mn;
      #pragma unroll
      for (int r = 0; r < 4; ++r){ p0[r] = exp2f(p0[r] - mn); p1[r] = exp2f(p1[r] - mn); }
      float ps = p0[0]+p0[1]+p0[2]+p0[3]+p1[0]+p1[1]+p1[2]+p1[3];
      ps += __shfl_xor(ps, 16);
      ps += __shfl_xor(ps, 32);
      l = l * al + ps;
      #pragma unroll
      for (int r = 0; r < 4; ++r){
        float ar = __shfl(al, hi*4 + r);
        a0[r] *= ar; a1[r] *= ar;
      }
      s16x8 pa;
      pa[0]=(short)f2bf(p0[0]); pa[1]=(short)f2bf(p0[1]); pa[2]=(short)f2bf(p0[2]); pa[3]=(short)f2bf(p0[3]);
      pa[4]=(short)f2bf(p1[0]); pa[5]=(short)f2bf(p1[1]); pa[6]=(short)f2bf(p1[2]); pa[7]=(short)f2bf(p1[3]);
      a0 = __builtin_amdgcn_mfma_f32_16x16x32_bf16(pa, vf0, a0, 0, 0, 0);
      a1 = __builtin_amdgcn_mfma_f32_16x16x32_bf16(pa, vf1, a1, 0, 0, 0);
    };
    step(qf0, acc00, acc01, m0, l0);
    step(qf1, acc10, acc11, m1, l1);
  }

  #pragma unroll
  for (int st = 0; st < 2; ++st){
    float l  = st ? l1 : l0;
    f32x4 a0 = st ? acc10 : acc00;
    f32x4 a1 = st ? acc11 : acc01;
    #pragma unroll
    for (int r = 0; r < 4; ++r){
      float ls = __shfl(l, hi*4 + r);
      float inv = 1.f / ls;
      int s = sw + st*16 + hi*4 + r;
      aoh[(size_t)s*DH + lo]      = f2bf(a0[r] * inv);
      aoh[(size_t)s*DH + lo + 16] = f2bf(a1[r] * inv);
    }
  }
}

// ---------------- kernel 6: proj GEMM + bias + residual ----------------
__global__ void k_proj(const unsigned short* __restrict__ aoT, const unsigned short* __restrict__ wp,
                       const float* __restrict__ pb, const float* __restrict__ x,
                       float* __restrict__ out){
  int lane = threadIdx.x & 63, wid = threadIdx.x >> 6;
  int lo = lane & 15, hi = lane >> 4;
  int b  = blockIdx.z;
  int o0 = blockIdx.y * 64 + wid * 16;
  int sb = blockIdx.x * 64;
  s16x8 af[4];
  #pragma unroll
  for (int kk = 0; kk < 4; ++kk)
    af[kk] = *(const s16x8*)(wp + (size_t)(o0+lo)*CH + kk*32 + hi*8);
  #pragma unroll
  for (int st = 0; st < 4; ++st){
    int s0 = sb + st*16;
    f32x4 acc = {0.f,0.f,0.f,0.f};
    #pragma unroll
    for (int kk = 0; kk < 4; ++kk){
      s16x8 bfr = *(const s16x8*)(aoT + (((size_t)(b*NH + kk))*S_TOT + s0 + lo)*DH + hi*8);
      acc = __builtin_amdgcn_mfma_f32_16x16x32_bf16(af[kk], bfr, acc, 0, 0, 0);
    }
    #pragma unroll
    for (int r = 0; r < 4; ++r){
      int o = o0 + hi*4 + r;
      size_t idx = ((size_t)(b*CH + o))*S_TOT + s0 + lo;
      out[idx] = acc[r] + pb[o] + x[idx];
    }
  }
}

extern "C" void kernel_launch(void* const* d_in, const int* in_sizes, int n_in,
                              void* d_out, int out_size, void* d_ws, size_t ws_size,
                              hipStream_t stream){
  const float* x     = (const float*)d_in[0];
  const float* nw    = (const float*)d_in[1];
  const float* nb    = (const float*)d_in[2];
  const float* qkvw  = (const float*)d_in[3];
  const float* qkvb  = (const float*)d_in[4];
  const float* projw = (const float*)d_in[5];
  const float* projb = (const float*)d_in[6];
  float* out = (float*)d_out;
  char* ws = (char*)d_ws;
  unsigned short* hT  = (unsigned short*)(ws);
  unsigned short* qT  = (unsigned short*)(ws + 2097152);
  unsigned short* kT  = (unsigned short*)(ws + 4194304);
  unsigned short* vv  = (unsigned short*)(ws + 6291456);
  unsigned short* aoT = (unsigned short*)(ws + 8388608);
  unsigned short* wq  = (unsigned short*)(ws + 10485760);
  unsigned short* wp  = (unsigned short*)(ws + 10485760 + 98304);
  float* stats        = (float*)(ws + 10485760 + 131072);

  hipLaunchKernelGGL(k_prep,    dim3(256),      dim3(256), 0, stream, qkvw, projw, wq, wp);
  hipLaunchKernelGGL(k_gnstats, dim3(64),       dim3(256), 0, stream, x, stats);
  hipLaunchKernelGGL(k_gnapply, dim3(128),      dim3(256), 0, stream, x, stats, nw, nb, hT);
  hipLaunchKernelGGL(k_qkv,     dim3(64, 6, 2), dim3(256), 0, stream, hT, wq, qkvb, qT, kT, vv);
  hipLaunchKernelGGL(k_attn,    dim3(8, 32),    dim3(256), 0, stream, qT, kT, vv, aoT);
  hipLaunchKernelGGL(k_proj,    dim3(64, 2, 2), dim3(256), 0, stream, aoT, wp, projb, x, out);
}

// Round 2
// 138.319 us; speedup vs baseline: 1.1207x; 1.1207x over previous
//
#include <hip/hip_runtime.h>
#include <stdint.h>

#define S_TOT 4096
#define CH 128
#define NH 4
#define DH 32

typedef __attribute__((ext_vector_type(4))) float f32x4;
typedef __attribute__((ext_vector_type(8))) short s16x8;
typedef __attribute__((ext_vector_type(4))) short s16x4;

__device__ __forceinline__ unsigned short f2bf(float f){
  union { float f; unsigned u; } v; v.f = f;
  unsigned r = v.u + 0x7fffu + ((v.u >> 16) & 1u);
  return (unsigned short)(r >> 16);
}
__device__ __forceinline__ unsigned pk2(float a, float b){
  return (unsigned)f2bf(a) | ((unsigned)f2bf(b) << 16);
}
__device__ __forceinline__ unsigned cvtpk(float a, float b){
  unsigned r;
  asm("v_cvt_pk_bf16_f32 %0, %1, %2" : "=v"(r) : "v"(a), "v"(b));
  return r;
}

// ---------------- kernel 1: fp32 -> bf16 weight conversion ----------------
__global__ void k_prep(const float* __restrict__ qkvw, const float* __restrict__ projw,
                       unsigned short* __restrict__ wq, unsigned short* __restrict__ wp){
  int i = blockIdx.x * 256 + threadIdx.x;
  if (i < 384*128) wq[i] = f2bf(qkvw[i]);
  int j = i - 384*128;
  if (j >= 0 && j < 128*128) wp[j] = f2bf(projw[j]);
}

// ---------------- kernel 2: groupnorm stats (mean, rstd per (b,g)) ----------------
__global__ void k_gnstats(const float* __restrict__ x, float* __restrict__ stats){
  int bg = blockIdx.x; // b*32+g ; group = 4 contiguous channels * 4096 = 16384 floats
  const float4* p = (const float4*)(x + (size_t)bg * 16384);
  float s = 0.f, ss = 0.f;
  #pragma unroll
  for (int i = 0; i < 16; ++i){
    float4 v = p[threadIdx.x + i*256];
    s  += v.x + v.y + v.z + v.w;
    ss += v.x*v.x + v.y*v.y + v.z*v.z + v.w*v.w;
  }
  #pragma unroll
  for (int m = 1; m < 64; m <<= 1){ s += __shfl_xor(s, m); ss += __shfl_xor(ss, m); }
  __shared__ float red[8];
  int wid = threadIdx.x >> 6;
  if ((threadIdx.x & 63) == 0){ red[wid*2] = s; red[wid*2+1] = ss; }
  __syncthreads();
  if (threadIdx.x == 0){
    float S = red[0]+red[2]+red[4]+red[6], SS = red[1]+red[3]+red[5]+red[7];
    float mean = S * (1.f/16384.f);
    float var  = SS * (1.f/16384.f) - mean*mean;
    stats[bg*2]   = mean;
    stats[bg*2+1] = rsqrtf(var + 1e-5f);
  }
}

// ---------------- kernel 3: apply GN + transpose to hT [B][S][C] bf16 ----------------
__global__ void k_gnapply(const float* __restrict__ x, const float* __restrict__ stats,
                          const float* __restrict__ nw, const float* __restrict__ nb,
                          unsigned short* __restrict__ hT){
  __shared__ float lds[64*129];
  int b  = blockIdx.x >> 6;
  int s0 = (blockIdx.x & 63) * 64;
  int sid = threadIdx.x & 63, cg = threadIdx.x >> 6;
  #pragma unroll 4
  for (int c4 = 0; c4 < 32; ++c4){
    int c = c4*4 + cg;
    float mean = stats[(b*32 + c4)*2], rstd = stats[(b*32 + c4)*2 + 1];
    float v = x[((size_t)(b*CH + c))*S_TOT + s0 + sid];
    v = (v - mean) * rstd * nw[c] + nb[c];
    lds[sid*129 + c] = v;
  }
  __syncthreads();
  int row = threadIdx.x >> 2, q = threadIdx.x & 3, c0 = q*32;
  unsigned short* dst = hT + ((size_t)(b*S_TOT) + s0 + row) * CH + c0;
  const float* src = lds + row*129 + c0;
  #pragma unroll
  for (int cc = 0; cc < 4; ++cc){
    uint4 w;
    w.x = pk2(src[cc*8+0], src[cc*8+1]);
    w.y = pk2(src[cc*8+2], src[cc*8+3]);
    w.z = pk2(src[cc*8+4], src[cc*8+5]);
    w.w = pk2(src[cc*8+6], src[cc*8+7]);
    *(uint4*)(dst + cc*8) = w;
  }
}

// ---------------- kernel 4: QKV GEMM (bf16 MFMA) ----------------
__global__ void k_qkv(const unsigned short* __restrict__ hT, const unsigned short* __restrict__ wq,
                      const float* __restrict__ qkvb,
                      unsigned short* __restrict__ qT, unsigned short* __restrict__ kT,
                      unsigned short* __restrict__ vv){
  const float SC = 0.17677669529663687f * 1.4426950408889634f; // (1/sqrt(32)) * log2(e)
  int lane = threadIdx.x & 63, wid = threadIdx.x >> 6;
  int lo = lane & 15, hi = lane >> 4;
  int b  = blockIdx.z;
  int o0 = blockIdx.y * 64 + wid * 16;
  int sb = blockIdx.x * 64;
  s16x8 af[4];
  #pragma unroll
  for (int kk = 0; kk < 4; ++kk)
    af[kk] = *(const s16x8*)(wq + (size_t)(o0+lo)*CH + kk*32 + hi*8);
  #pragma unroll
  for (int st = 0; st < 4; ++st){
    int s0 = sb + st*16;
    const unsigned short* hrow = hT + ((size_t)(b*S_TOT) + s0 + lo) * CH + hi*8;
    f32x4 acc = {0.f,0.f,0.f,0.f};
    #pragma unroll
    for (int kk = 0; kk < 4; ++kk){
      s16x8 bfr = *(const s16x8*)(hrow + kk*32);
      acc = __builtin_amdgcn_mfma_f32_16x16x32_bf16(af[kk], bfr, acc, 0, 0, 0);
    }
    int s = s0 + lo;
    #pragma unroll
    for (int r = 0; r < 4; ++r){
      int o = o0 + hi*4 + r;
      float val = acc[r] + qkvb[o];
      if (o < 128){
        int h = o >> 5, d = o & 31;
        qT[(((size_t)(b*NH + h))*S_TOT + s)*DH + d] = f2bf(val * SC);
      } else if (o < 256){
        int o2 = o - 128, h = o2 >> 5, d = o2 & 31;
        kT[(((size_t)(b*NH + h))*S_TOT + s)*DH + d] = f2bf(val);
      } else {
        int o3 = o - 256, h = o3 >> 5, d = o3 & 31;
        vv[(((size_t)(b*NH + h))*DH + d)*S_TOT + s] = f2bf(val);
      }
    }
  }
}

// ---------------- kernel 5: two-pass flash attention, split-KV=2 ----------------
// pass1: running per-query max (register-only). pass2: exp2(S-m), l accum, PV. No cross-lane in loops.
__global__ void __launch_bounds__(256) k_attn(const unsigned short* __restrict__ qT,
                                              const unsigned short* __restrict__ kT,
                                              const unsigned short* __restrict__ vv,
                                              float* __restrict__ po,
                                              float* __restrict__ ml){
  int lane = threadIdx.x & 63, wid = threadIdx.x >> 6;
  int lo = lane & 15, hi = lane >> 4;
  int bh = blockIdx.x;                 // wgid%8 == head -> one head per XCD
  int sw = blockIdx.y * 128 + wid * 32;
  int sp = blockIdx.z;
  int tbeg = sp * 2048, tend = tbeg + 2048;
  const unsigned short* qh = qT + (size_t)bh * S_TOT * DH;
  const unsigned short* kh = kT + (size_t)bh * S_TOT * DH;
  const unsigned short* vh = vv + (size_t)bh * DH * S_TOT;

  s16x8 qf0 = *(const s16x8*)(qh + (size_t)(sw + lo)*DH + hi*8);
  s16x8 qf1 = *(const s16x8*)(qh + (size_t)(sw + 16 + lo)*DH + hi*8);
  const f32x4 z = {0.f,0.f,0.f,0.f};

  // ---- pass 1: max ----
  float mx0 = -1e30f, mx1 = -1e30f;
  for (int t0 = tbeg; t0 < tend; t0 += 32){
    s16x8 kf0 = *(const s16x8*)(kh + (size_t)(t0 + lo)*DH + hi*8);
    s16x8 kf1 = *(const s16x8*)(kh + (size_t)(t0 + 16 + lo)*DH + hi*8);
    f32x4 p0 = __builtin_amdgcn_mfma_f32_16x16x32_bf16(kf0, qf0, z, 0, 0, 0);
    f32x4 p1 = __builtin_amdgcn_mfma_f32_16x16x32_bf16(kf1, qf0, z, 0, 0, 0);
    mx0 = fmaxf(mx0, fmaxf(fmaxf(fmaxf(p0[0],p0[1]),fmaxf(p0[2],p0[3])),
                           fmaxf(fmaxf(p1[0],p1[1]),fmaxf(p1[2],p1[3]))));
    f32x4 q0 = __builtin_amdgcn_mfma_f32_16x16x32_bf16(kf0, qf1, z, 0, 0, 0);
    f32x4 q1 = __builtin_amdgcn_mfma_f32_16x16x32_bf16(kf1, qf1, z, 0, 0, 0);
    mx1 = fmaxf(mx1, fmaxf(fmaxf(fmaxf(q0[0],q0[1]),fmaxf(q0[2],q0[3])),
                           fmaxf(fmaxf(q1[0],q1[1]),fmaxf(q1[2],q1[3]))));
  }
  mx0 = fmaxf(mx0, __shfl_xor(mx0, 16)); mx0 = fmaxf(mx0, __shfl_xor(mx0, 32));
  mx1 = fmaxf(mx1, __shfl_xor(mx1, 16)); mx1 = fmaxf(mx1, __shfl_xor(mx1, 32));

  // ---- pass 2: exp + PV ----
  f32x4 acc00 = z, acc01 = z, acc10 = z, acc11 = z;
  float l0 = 0.f, l1 = 0.f;
  for (int t0 = tbeg; t0 < tend; t0 += 32){
    s16x8 kf0 = *(const s16x8*)(kh + (size_t)(t0 + lo)*DH + hi*8);
    s16x8 kf1 = *(const s16x8*)(kh + (size_t)(t0 + 16 + lo)*DH + hi*8);
    s16x4 va0 = *(const s16x4*)(vh + (size_t)lo*S_TOT + t0 + hi*4);
    s16x4 vb0 = *(const s16x4*)(vh + (size_t)lo*S_TOT + t0 + 16 + hi*4);
    s16x4 va1 = *(const s16x4*)(vh + (size_t)(lo+16)*S_TOT + t0 + hi*4);
    s16x4 vb1 = *(const s16x4*)(vh + (size_t)(lo+16)*S_TOT + t0 + 16 + hi*4);
    s16x8 vf0 = __builtin_shufflevector(va0, vb0, 0,1,2,3,4,5,6,7);
    s16x8 vf1 = __builtin_shufflevector(va1, vb1, 0,1,2,3,4,5,6,7);

    f32x4 p0 = __builtin_amdgcn_mfma_f32_16x16x32_bf16(kf0, qf0, z, 0, 0, 0);
    f32x4 p1 = __builtin_amdgcn_mfma_f32_16x16x32_bf16(kf1, qf0, z, 0, 0, 0);
    #pragma unroll
    for (int r = 0; r < 4; ++r){ p0[r] = exp2f(p0[r] - mx0); p1[r] = exp2f(p1[r] - mx0); }
    l0 += p0[0]+p0[1]+p0[2]+p0[3]+p1[0]+p1[1]+p1[2]+p1[3];
    union { unsigned u[4]; s16x8 v; } pk0;
    pk0.u[0] = cvtpk(p0[0],p0[1]); pk0.u[1] = cvtpk(p0[2],p0[3]);
    pk0.u[2] = cvtpk(p1[0],p1[1]); pk0.u[3] = cvtpk(p1[2],p1[3]);
    acc00 = __builtin_amdgcn_mfma_f32_16x16x32_bf16(pk0.v, vf0, acc00, 0, 0, 0);
    acc01 = __builtin_amdgcn_mfma_f32_16x16x32_bf16(pk0.v, vf1, acc01, 0, 0, 0);

    f32x4 q0 = __builtin_amdgcn_mfma_f32_16x16x32_bf16(kf0, qf1, z, 0, 0, 0);
    f32x4 q1 = __builtin_amdgcn_mfma_f32_16x16x32_bf16(kf1, qf1, z, 0, 0, 0);
    #pragma unroll
    for (int r = 0; r < 4; ++r){ q0[r] = exp2f(q0[r] - mx1); q1[r] = exp2f(q1[r] - mx1); }
    l1 += q0[0]+q0[1]+q0[2]+q0[3]+q1[0]+q1[1]+q1[2]+q1[3];
    union { unsigned u[4]; s16x8 v; } pk1;
    pk1.u[0] = cvtpk(q0[0],q0[1]); pk1.u[1] = cvtpk(q0[2],q0[3]);
    pk1.u[2] = cvtpk(q1[0],q1[1]); pk1.u[3] = cvtpk(q1[2],q1[3]);
    acc10 = __builtin_amdgcn_mfma_f32_16x16x32_bf16(pk1.v, vf0, acc10, 0, 0, 0);
    acc11 = __builtin_amdgcn_mfma_f32_16x16x32_bf16(pk1.v, vf1, acc11, 0, 0, 0);
  }
  l0 += __shfl_xor(l0, 16); l0 += __shfl_xor(l0, 32);
  l1 += __shfl_xor(l1, 16); l1 += __shfl_xor(l1, 32);

  // ---- write partials ----
  float* pob = po + (size_t)(bh*2 + sp) * S_TOT * DH;
  #pragma unroll
  for (int r = 0; r < 4; ++r){
    int s0r = sw + hi*4 + r;
    pob[(size_t)s0r*DH + lo]      = acc00[r];
    pob[(size_t)s0r*DH + lo + 16] = acc01[r];
    int s1r = sw + 16 + hi*4 + r;
    pob[(size_t)s1r*DH + lo]      = acc10[r];
    pob[(size_t)s1r*DH + lo + 16] = acc11[r];
  }
  if (hi == 0){
    size_t base = ((size_t)(bh*2 + sp) * S_TOT + sw + lo) * 2;
    ml[base]     = mx0;
    ml[base + 1] = l0;
    size_t base1 = ((size_t)(bh*2 + sp) * S_TOT + sw + 16 + lo) * 2;
    ml[base1]     = mx1;
    ml[base1 + 1] = l1;
  }
}

// ---------------- kernel 5b: combine split-KV partials -> aoT bf16 ----------------
__global__ void k_comb(const float* __restrict__ po, const float* __restrict__ ml,
                       unsigned short* __restrict__ aoT){
  int idx = blockIdx.x * 256 + threadIdx.x;   // (bh*4096 + s)*32 + d
  int d = idx & 31;
  int s = (idx >> 5) & 4095;
  int bh = idx >> 17;
  size_t b0 = (size_t)(bh*2 + 0) * S_TOT + s;
  size_t b1 = (size_t)(bh*2 + 1) * S_TOT + s;
  float m0 = ml[b0*2], l0v = ml[b0*2+1];
  float m1 = ml[b1*2], l1v = ml[b1*2+1];
  float M = fmaxf(m0, m1);
  float e0 = exp2f(m0 - M), e1 = exp2f(m1 - M);
  float L = l0v*e0 + l1v*e1;
  float v = (po[b0*DH + d]*e0 + po[b1*DH + d]*e1) / L;
  aoT[idx] = f2bf(v);
}

// ---------------- kernel 6: proj GEMM + bias + residual ----------------
__global__ void k_proj(const unsigned short* __restrict__ aoT, const unsigned short* __restrict__ wp,
                       const float* __restrict__ pb, const float* __restrict__ x,
                       float* __restrict__ out){
  int lane = threadIdx.x & 63, wid = threadIdx.x >> 6;
  int lo = lane & 15, hi = lane >> 4;
  int b  = blockIdx.z;
  int o0 = blockIdx.y * 64 + wid * 16;
  int sb = blockIdx.x * 64;
  s16x8 af[4];
  #pragma unroll
  for (int kk = 0; kk < 4; ++kk)
    af[kk] = *(const s16x8*)(wp + (size_t)(o0+lo)*CH + kk*32 + hi*8);
  #pragma unroll
  for (int st = 0; st < 4; ++st){
    int s0 = sb + st*16;
    f32x4 acc = {0.f,0.f,0.f,0.f};
    #pragma unroll
    for (int kk = 0; kk < 4; ++kk){
      s16x8 bfr = *(const s16x8*)(aoT + (((size_t)(b*NH + kk))*S_TOT + s0 + lo)*DH + hi*8);
      acc = __builtin_amdgcn_mfma_f32_16x16x32_bf16(af[kk], bfr, acc, 0, 0, 0);
    }
    #pragma unroll
    for (int r = 0; r < 4; ++r){
      int o = o0 + hi*4 + r;
      size_t idx = ((size_t)(b*CH + o))*S_TOT + s0 + lo;
      out[idx] = acc[r] + pb[o] + x[idx];
    }
  }
}

extern "C" void kernel_launch(void* const* d_in, const int* in_sizes, int n_in,
                              void* d_out, int out_size, void* d_ws, size_t ws_size,
                              hipStream_t stream){
  const float* x     = (const float*)d_in[0];
  const float* nw    = (const float*)d_in[1];
  const float* nb    = (const float*)d_in[2];
  const float* qkvw  = (const float*)d_in[3];
  const float* qkvb  = (const float*)d_in[4];
  const float* projw = (const float*)d_in[5];
  const float* projb = (const float*)d_in[6];
  float* out = (float*)d_out;
  char* ws = (char*)d_ws;
  unsigned short* hT  = (unsigned short*)(ws);
  unsigned short* qT  = (unsigned short*)(ws + 2097152);
  unsigned short* kT  = (unsigned short*)(ws + 4194304);
  unsigned short* vv  = (unsigned short*)(ws + 6291456);
  unsigned short* aoT = (unsigned short*)(ws + 8388608);
  unsigned short* wq  = (unsigned short*)(ws + 10485760);
  unsigned short* wp  = (unsigned short*)(ws + 10485760 + 98304);
  float* stats        = (float*)(ws + 10485760 + 131072);
  float* ml           = (float*)(ws + 10485760 + 196608);           // 512 KB
  float* po           = (float*)(ws + 10485760 + 196608 + 524288);  // 8 MB

  hipLaunchKernelGGL(k_prep,    dim3(256),      dim3(256), 0, stream, qkvw, projw, wq, wp);
  hipLaunchKernelGGL(k_gnstats, dim3(64),       dim3(256), 0, stream, x, stats);
  hipLaunchKernelGGL(k_gnapply, dim3(128),      dim3(256), 0, stream, x, stats, nw, nb, hT);
  hipLaunchKernelGGL(k_qkv,     dim3(64, 6, 2), dim3(256), 0, stream, hT, wq, qkvb, qT, kT, vv);
  hipLaunchKernelGGL(k_attn,    dim3(8, 32, 2), dim3(256), 0, stream, qT, kT, vv, po, ml);
  hipLaunchKernelGGL(k_comb,    dim3(4096),     dim3(256), 0, stream, po, ml, (unsigned short*)aoT);
  hipLaunchKernelGGL(k_proj,    dim3(64, 2, 2), dim3(256), 0, stream, aoT, wp, projb, x, out);
}

// Round 3
// 95.146 us; speedup vs baseline: 1.6293x; 1.4538x over previous
//
#include <hip/hip_runtime.h>
#include <stdint.h>

#define S_TOT 4096
#define CH 128
#define NH 4
#define DH 32

typedef __attribute__((ext_vector_type(4))) float f32x4;
typedef __attribute__((ext_vector_type(8))) short s16x8;
typedef __attribute__((ext_vector_type(4))) short s16x4;

__device__ __forceinline__ unsigned short f2bf(float f){
  union { float f; unsigned u; } v; v.f = f;
  unsigned r = v.u + 0x7fffu + ((v.u >> 16) & 1u);
  return (unsigned short)(r >> 16);
}
__device__ __forceinline__ unsigned pk2(float a, float b){
  return (unsigned)f2bf(a) | ((unsigned)f2bf(b) << 16);
}
__device__ __forceinline__ unsigned cvtpk(float a, float b){
  unsigned r;
  asm("v_cvt_pk_bf16_f32 %0, %1, %2" : "=v"(r) : "v"(a), "v"(b));
  return r;
}

// ---------------- kernel 1: fp32 -> bf16 weight conversion ----------------
__global__ void k_prep(const float* __restrict__ qkvw, const float* __restrict__ projw,
                       unsigned short* __restrict__ wq, unsigned short* __restrict__ wp){
  int i = blockIdx.x * 256 + threadIdx.x;
  if (i < 384*128) wq[i] = f2bf(qkvw[i]);
  int j = i - 384*128;
  if (j >= 0 && j < 128*128) wp[j] = f2bf(projw[j]);
}

// ---------------- kernel 2: groupnorm stats (mean, rstd per (b,g)) ----------------
__global__ void k_gnstats(const float* __restrict__ x, float* __restrict__ stats){
  int bg = blockIdx.x;
  const float4* p = (const float4*)(x + (size_t)bg * 16384);
  float s = 0.f, ss = 0.f;
  #pragma unroll
  for (int i = 0; i < 16; ++i){
    float4 v = p[threadIdx.x + i*256];
    s  += v.x + v.y + v.z + v.w;
    ss += v.x*v.x + v.y*v.y + v.z*v.z + v.w*v.w;
  }
  #pragma unroll
  for (int m = 1; m < 64; m <<= 1){ s += __shfl_xor(s, m); ss += __shfl_xor(ss, m); }
  __shared__ float red[8];
  int wid = threadIdx.x >> 6;
  if ((threadIdx.x & 63) == 0){ red[wid*2] = s; red[wid*2+1] = ss; }
  __syncthreads();
  if (threadIdx.x == 0){
    float S = red[0]+red[2]+red[4]+red[6], SS = red[1]+red[3]+red[5]+red[7];
    float mean = S * (1.f/16384.f);
    float var  = SS * (1.f/16384.f) - mean*mean;
    stats[bg*2]   = mean;
    stats[bg*2+1] = rsqrtf(var + 1e-5f);
  }
}

// ---------------- kernel 3: apply GN + transpose to hT [B][S][C] bf16 ----------------
__global__ void k_gnapply(const float* __restrict__ x, const float* __restrict__ stats,
                          const float* __restrict__ nw, const float* __restrict__ nb,
                          unsigned short* __restrict__ hT){
  __shared__ float lds[64*129];
  int b  = blockIdx.x >> 6;
  int s0 = (blockIdx.x & 63) * 64;
  int sid = threadIdx.x & 63, cg = threadIdx.x >> 6;
  #pragma unroll 4
  for (int c4 = 0; c4 < 32; ++c4){
    int c = c4*4 + cg;
    float mean = stats[(b*32 + c4)*2], rstd = stats[(b*32 + c4)*2 + 1];
    float v = x[((size_t)(b*CH + c))*S_TOT + s0 + sid];
    v = (v - mean) * rstd * nw[c] + nb[c];
    lds[sid*129 + c] = v;
  }
  __syncthreads();
  int row = threadIdx.x >> 2, q = threadIdx.x & 3, c0 = q*32;
  unsigned short* dst = hT + ((size_t)(b*S_TOT) + s0 + row) * CH + c0;
  const float* src = lds + row*129 + c0;
  #pragma unroll
  for (int cc = 0; cc < 4; ++cc){
    uint4 w;
    w.x = pk2(src[cc*8+0], src[cc*8+1]);
    w.y = pk2(src[cc*8+2], src[cc*8+3]);
    w.z = pk2(src[cc*8+4], src[cc*8+5]);
    w.w = pk2(src[cc*8+6], src[cc*8+7]);
    *(uint4*)(dst + cc*8) = w;
  }
}

// ---------------- kernel 4: QKV GEMM (bf16 MFMA) ----------------
// q scaled by scale*log2e; q/k stored [b][h][s][d]; v stored pre-swizzled to PV B-fragment order.
__global__ void k_qkv(const unsigned short* __restrict__ hT, const unsigned short* __restrict__ wq,
                      const float* __restrict__ qkvb,
                      unsigned short* __restrict__ qT, unsigned short* __restrict__ kT,
                      unsigned short* __restrict__ vz){
  const float SC = 0.17677669529663687f * 1.4426950408889634f; // (1/sqrt(32)) * log2(e)
  int lane = threadIdx.x & 63, wid = threadIdx.x >> 6;
  int lo = lane & 15, hi = lane >> 4;
  int b  = blockIdx.z;
  int o0 = blockIdx.y * 64 + wid * 16;
  int sb = blockIdx.x * 64;
  s16x8 af[4];
  #pragma unroll
  for (int kk = 0; kk < 4; ++kk)
    af[kk] = *(const s16x8*)(wq + (size_t)(o0+lo)*CH + kk*32 + hi*8);
  #pragma unroll
  for (int st = 0; st < 4; ++st){
    int s0 = sb + st*16;
    const unsigned short* hrow = hT + ((size_t)(b*S_TOT) + s0 + lo) * CH + hi*8;
    f32x4 acc = {0.f,0.f,0.f,0.f};
    #pragma unroll
    for (int kk = 0; kk < 4; ++kk){
      s16x8 bfr = *(const s16x8*)(hrow + kk*32);
      acc = __builtin_amdgcn_mfma_f32_16x16x32_bf16(af[kk], bfr, acc, 0, 0, 0);
    }
    int s = s0 + lo;
    #pragma unroll
    for (int r = 0; r < 4; ++r){
      int o = o0 + hi*4 + r;
      float val = acc[r] + qkvb[o];
      if (o < 128){
        int h = o >> 5, d = o & 31;
        qT[(((size_t)(b*NH + h))*S_TOT + s)*DH + d] = f2bf(val * SC);
      } else if (o < 256){
        int o2 = o - 128, h = o2 >> 5, d = o2 & 31;
        kT[(((size_t)(b*NH + h))*S_TOT + s)*DH + d] = f2bf(val);
      } else {
        // V pre-swizzled: vz[bh][d][tile][hi2*8+j2], slot order = PV B-fragment order
        int o3 = o - 256, h = o3 >> 5, d = o3 & 31;
        int tt = s >> 5, pos = s & 31;
        int hi2 = (pos & 15) >> 2;
        int j2  = (pos & 3) + ((pos & 16) ? 4 : 0);
        vz[((((size_t)(b*NH + h))*DH + d)*128 + tt)*32 + hi2*8 + j2] = f2bf(val);
      }
    }
  }
}

// ---------------- kernel 5: single-pass no-max flash attention, split-KV=4 ----------------
// p = exp2(s) directly (scores bounded, fp32 range is ample). l accumulated via MFMA vs ones.
__global__ void __launch_bounds__(256) k_attn(const unsigned short* __restrict__ qT,
                                              const unsigned short* __restrict__ kT,
                                              const unsigned short* __restrict__ vz,
                                              float* __restrict__ po,
                                              float* __restrict__ ls){
  int lane = threadIdx.x & 63;
  int wid = threadIdx.x >> 6;
  int lo = lane & 15, hi = lane >> 4;
  int bh = blockIdx.x;                 // wgid%8 == head -> one head per XCD
  int sw = blockIdx.y * 128 + wid * 32;
  int sp = blockIdx.z;
  int tb = sp * 32, te = tb + 32;      // tile indices (32 t each) -> 1024 t per split
  const unsigned short* qh = qT + (size_t)bh * S_TOT * DH;
  const unsigned short* kh = kT + (size_t)bh * S_TOT * DH;
  const unsigned short* vh = vz + (size_t)bh * S_TOT * DH;

  s16x8 qf0 = *(const s16x8*)(qh + (size_t)(sw + lo)*DH + hi*8);
  s16x8 qf1 = *(const s16x8*)(qh + (size_t)(sw + 16 + lo)*DH + hi*8);
  const f32x4 z = {0.f,0.f,0.f,0.f};
  f32x4 acc00 = z, acc01 = z, acc10 = z, acc11 = z, accL0 = z, accL1 = z;
  s16x8 onesf;
  #pragma unroll
  for (int i = 0; i < 8; ++i) onesf[i] = (short)0x3F80; // bf16 1.0

  // prefetch first tile
  const unsigned short* kp = kh + (size_t)tb*32*DH;
  s16x8 kf0 = *(const s16x8*)(kp + (size_t)lo*DH + hi*8);
  s16x8 kf1 = *(const s16x8*)(kp + (size_t)(16 + lo)*DH + hi*8);
  s16x8 vf0 = *(const s16x8*)(vh + ((size_t)lo*128 + tb)*32 + hi*8);
  s16x8 vf1 = *(const s16x8*)(vh + (((size_t)lo+16)*128 + tb)*32 + hi*8);

  for (int tile = tb; tile < te; ++tile){
    int tn = (tile + 1 < te) ? tile + 1 : tb;
    const unsigned short* kpn = kh + (size_t)tn*32*DH;
    s16x8 kn0 = *(const s16x8*)(kpn + (size_t)lo*DH + hi*8);
    s16x8 kn1 = *(const s16x8*)(kpn + (size_t)(16 + lo)*DH + hi*8);
    s16x8 vn0 = *(const s16x8*)(vh + ((size_t)lo*128 + tn)*32 + hi*8);
    s16x8 vn1 = *(const s16x8*)(vh + (((size_t)lo+16)*128 + tn)*32 + hi*8);

    f32x4 p0 = __builtin_amdgcn_mfma_f32_16x16x32_bf16(kf0, qf0, z, 0, 0, 0);
    f32x4 p1 = __builtin_amdgcn_mfma_f32_16x16x32_bf16(kf1, qf0, z, 0, 0, 0);
    f32x4 r0 = __builtin_amdgcn_mfma_f32_16x16x32_bf16(kf0, qf1, z, 0, 0, 0);
    f32x4 r1 = __builtin_amdgcn_mfma_f32_16x16x32_bf16(kf1, qf1, z, 0, 0, 0);
    #pragma unroll
    for (int r = 0; r < 4; ++r){
      p0[r] = __builtin_amdgcn_exp2f(p0[r]);
      p1[r] = __builtin_amdgcn_exp2f(p1[r]);
      r0[r] = __builtin_amdgcn_exp2f(r0[r]);
      r1[r] = __builtin_amdgcn_exp2f(r1[r]);
    }
    union { unsigned u[4]; s16x8 v; } pa0, pa1;
    pa0.u[0] = cvtpk(p0[0],p0[1]); pa0.u[1] = cvtpk(p0[2],p0[3]);
    pa0.u[2] = cvtpk(p1[0],p1[1]); pa0.u[3] = cvtpk(p1[2],p1[3]);
    pa1.u[0] = cvtpk(r0[0],r0[1]); pa1.u[1] = cvtpk(r0[2],r0[3]);
    pa1.u[2] = cvtpk(r1[0],r1[1]); pa1.u[3] = cvtpk(r1[2],r1[3]);
    acc00 = __builtin_amdgcn_mfma_f32_16x16x32_bf16(pa0.v, vf0, acc00, 0, 0, 0);
    acc01 = __builtin_amdgcn_mfma_f32_16x16x32_bf16(pa0.v, vf1, acc01, 0, 0, 0);
    acc10 = __builtin_amdgcn_mfma_f32_16x16x32_bf16(pa1.v, vf0, acc10, 0, 0, 0);
    acc11 = __builtin_amdgcn_mfma_f32_16x16x32_bf16(pa1.v, vf1, acc11, 0, 0, 0);
    accL0 = __builtin_amdgcn_mfma_f32_16x16x32_bf16(pa0.v, onesf, accL0, 0, 0, 0);
    accL1 = __builtin_amdgcn_mfma_f32_16x16x32_bf16(pa1.v, onesf, accL1, 0, 0, 0);

    kf0 = kn0; kf1 = kn1; vf0 = vn0; vf1 = vn1;
  }

  float* pob = po + (size_t)(bh*4 + sp) * S_TOT * DH;
  float* lsb = ls + (size_t)(bh*4 + sp) * S_TOT;
  #pragma unroll
  for (int r = 0; r < 4; ++r){
    int s0r = sw + hi*4 + r;
    pob[(size_t)s0r*DH + lo]      = acc00[r];
    pob[(size_t)s0r*DH + lo + 16] = acc01[r];
    int s1r = sw + 16 + hi*4 + r;
    pob[(size_t)s1r*DH + lo]      = acc10[r];
    pob[(size_t)s1r*DH + lo + 16] = acc11[r];
  }
  if (lo == 0){
    #pragma unroll
    for (int r = 0; r < 4; ++r){
      lsb[sw + hi*4 + r]      = accL0[r];
      lsb[sw + 16 + hi*4 + r] = accL1[r];
    }
  }
}

// ---------------- kernel 5b: combine split-KV partials -> aoT bf16 ----------------
__global__ void k_comb(const float* __restrict__ po, const float* __restrict__ ls,
                       unsigned short* __restrict__ aoT){
  int idx = blockIdx.x * 256 + threadIdx.x;   // (bh*4096 + s)*32 + d
  int d = idx & 31;
  int s = (idx >> 5) & 4095;
  int bh = idx >> 17;
  float l = 0.f, v = 0.f;
  #pragma unroll
  for (int sp = 0; sp < 4; ++sp){
    size_t b = (size_t)(bh*4 + sp) * S_TOT + s;
    l += ls[b];
    v += po[b*DH + d];
  }
  aoT[idx] = f2bf(v / l);
}

// ---------------- kernel 6: proj GEMM + bias + residual ----------------
__global__ void k_proj(const unsigned short* __restrict__ aoT, const unsigned short* __restrict__ wp,
                       const float* __restrict__ pb, const float* __restrict__ x,
                       float* __restrict__ out){
  int lane = threadIdx.x & 63, wid = threadIdx.x >> 6;
  int lo = lane & 15, hi = lane >> 4;
  int b  = blockIdx.z;
  int o0 = blockIdx.y * 64 + wid * 16;
  int sb = blockIdx.x * 64;
  s16x8 af[4];
  #pragma unroll
  for (int kk = 0; kk < 4; ++kk)
    af[kk] = *(const s16x8*)(wp + (size_t)(o0+lo)*CH + kk*32 + hi*8);
  #pragma unroll
  for (int st = 0; st < 4; ++st){
    int s0 = sb + st*16;
    f32x4 acc = {0.f,0.f,0.f,0.f};
    #pragma unroll
    for (int kk = 0; kk < 4; ++kk){
      s16x8 bfr = *(const s16x8*)(aoT + (((size_t)(b*NH + kk))*S_TOT + s0 + lo)*DH + hi*8);
      acc = __builtin_amdgcn_mfma_f32_16x16x32_bf16(af[kk], bfr, acc, 0, 0, 0);
    }
    #pragma unroll
    for (int r = 0; r < 4; ++r){
      int o = o0 + hi*4 + r;
      size_t idx = ((size_t)(b*CH + o))*S_TOT + s0 + lo;
      out[idx] = acc[r] + pb[o] + x[idx];
    }
  }
}

extern "C" void kernel_launch(void* const* d_in, const int* in_sizes, int n_in,
                              void* d_out, int out_size, void* d_ws, size_t ws_size,
                              hipStream_t stream){
  const float* x     = (const float*)d_in[0];
  const float* nw    = (const float*)d_in[1];
  const float* nb    = (const float*)d_in[2];
  const float* qkvw  = (const float*)d_in[3];
  const float* qkvb  = (const float*)d_in[4];
  const float* projw = (const float*)d_in[5];
  const float* projb = (const float*)d_in[6];
  float* out = (float*)d_out;
  char* ws = (char*)d_ws;
  const size_t MB = 1048576;
  unsigned short* qT  = (unsigned short*)(ws);            // 2MB
  unsigned short* kT  = (unsigned short*)(ws + 2*MB);     // 2MB
  unsigned short* vz  = (unsigned short*)(ws + 4*MB);     // 2MB
  unsigned short* aoT = (unsigned short*)(ws + 6*MB);     // 2MB
  unsigned short* wq  = (unsigned short*)(ws + 8*MB);           // 96KB
  unsigned short* wp  = (unsigned short*)(ws + 8*MB + 131072);  // 32KB
  float* stats        = (float*)(ws + 8*MB + 196608);           // 512B
  float* ls           = (float*)(ws + 8*MB + 262144);           // 512KB
  unsigned short* hT  = (unsigned short*)(ws + 9*MB);     // 2MB
  float* po           = (float*)(ws + 11*MB);             // 16MB (total 27MB)

  hipLaunchKernelGGL(k_prep,    dim3(256),      dim3(256), 0, stream, qkvw, projw, wq, wp);
  hipLaunchKernelGGL(k_gnstats, dim3(64),       dim3(256), 0, stream, x, stats);
  hipLaunchKernelGGL(k_gnapply, dim3(128),      dim3(256), 0, stream, x, stats, nw, nb, hT);
  hipLaunchKernelGGL(k_qkv,     dim3(64, 6, 2), dim3(256), 0, stream, hT, wq, qkvb, qT, kT, vz);
  hipLaunchKernelGGL(k_attn,    dim3(8, 32, 4), dim3(256), 0, stream, qT, kT, vz, po, ls);
  hipLaunchKernelGGL(k_comb,    dim3(4096),     dim3(256), 0, stream, po, ls, aoT);
  hipLaunchKernelGGL(k_proj,    dim3(64, 2, 2), dim3(256), 0, stream, aoT, wp, projb, x, out);
}